// Round 10
// baseline (192.963 us; speedup 1.0000x reference)
//
#include <hip/hip_runtime.h>
#include <math.h>

#define B_   2
#define S_   2048
#define H_   1024
#define NH_  16
#define NKV_ 4
#define HD_  64
#define R_   (NH_ / NKV_)   // 4 q-heads per kv-head
#define QKVW 1536           // qkv row width (q 0..1023 | k 1024..1279 | v 1280..1535)

typedef __attribute__((ext_vector_type(8))) short bf16x8;
typedef __attribute__((ext_vector_type(4))) float f32x4;

__device__ inline short f2bf(float f) {
    unsigned u = __float_as_uint(f);
    u += 0x7FFF + ((u >> 16) & 1);     // RNE to bf16
    return (short)(u >> 16);
}

// native 2^x (v_exp_f32)
__device__ inline float exp2fast(float x) {
#if __has_builtin(__builtin_amdgcn_exp2f)
    return __builtin_amdgcn_exp2f(x);
#else
    float r; asm volatile("v_exp_f32 %0, %1\n\ts_nop 1" : "=v"(r) : "v"(x)); return r;
#endif
}

// pack 2 fp32 -> 2 bf16 (RNE) in one instr
__device__ inline unsigned cvt_pk_bf16(float lo, float hi) {
    unsigned r;
    asm("v_cvt_pk_bf16_f32 %0, %1, %2" : "=v"(r) : "v"(lo), "v"(hi));
    return r;
}

#define LOG2E 1.4426950408889634f

// async global->LDS, 16 B per lane (m97/m104 semantics).
__device__ inline void gload_lds16(const void* gptr, void* lptr) {
    __builtin_amdgcn_global_load_lds(
        (const __attribute__((address_space(1))) unsigned int*)gptr,
        (__attribute__((address_space(3))) unsigned int*)lptr,
        16, 0, 0);
}

// ---------------------------------------------------------------------------
// Weight transposes only (x-convert folded into gemm1). 640 blocks of
// 64x64 tiles: Wq -> Wqkvt[0:1024), Wk -> [1024:1280), Wv -> [1280:1536),
// Wo -> Wot.
// ---------------------------------------------------------------------------
__global__ __launch_bounds__(256) void tconv_all(const float* __restrict__ Wq,
                                                 const float* __restrict__ Wk,
                                                 const float* __restrict__ Wv,
                                                 const float* __restrict__ Wo,
                                                 short* __restrict__ Wqkvt,
                                                 short* __restrict__ Wot) {
    __shared__ short T[64][68];
    const int bx = blockIdx.x;
    const int tid = threadIdx.x;
    const float* W; short* Wt; int N, idx;
    if (bx < 256)      { W = Wq; Wt = Wqkvt;                     N = 1024; idx = bx; }
    else if (bx < 320) { W = Wk; Wt = Wqkvt + 1024 * 1024;       N = 256;  idx = bx - 256; }
    else if (bx < 384) { W = Wv; Wt = Wqkvt + 1280 * 1024;       N = 256;  idx = bx - 320; }
    else               { W = Wo; Wt = Wot;                       N = 1024; idx = bx - 384; }
    const int ntiles = N >> 6;
    const int n0 = (idx % ntiles) * 64;
    const int k0 = (idx / ntiles) * 64;

    const int r  = tid >> 4;
    const int c4 = (tid & 15) * 4;
#pragma unroll
    for (int t = 0; t < 4; t++) {
        int row = t * 16 + r;
        float4 v = *(const float4*)&W[(size_t)(k0 + row) * N + n0 + c4];
        T[c4 + 0][row] = f2bf(v.x);
        T[c4 + 1][row] = f2bf(v.y);
        T[c4 + 2][row] = f2bf(v.z);
        T[c4 + 3][row] = f2bf(v.w);
    }
    __syncthreads();
#pragma unroll
    for (int t = 0; t < 4; t++) {
        int row = t * 16 + r;          // n index
        short4 o = *(short4*)&T[row][c4];
        *(short4*)&Wt[(size_t)(n0 + row) * 1024 + k0 + c4] = o;
    }
}

// ---------------------------------------------------------------------------
// Fused GEMM1 v5: qkv = bf16(x) @ Wqkvt^T, 64x128 tile, BK=32, 2-phase
// dbuf. A staged from fp32 x via register convert (R1-proven map) into the
// A double-buffer — xb pass and its 16 MB round-trip eliminated. B via
// glds. RoPE epilogue q/k; v transposed-scatter into Vtg.
// ---------------------------------------------------------------------------
__global__ __launch_bounds__(256) void gemm1_fused(const float* __restrict__ x,
                                                   const short* __restrict__ Bt,
                                                   short* __restrict__ qkv,
                                                   short* __restrict__ Vtg,
                                                   const float* __restrict__ cosb,
                                                   const float* __restrict__ sinb) {
    __shared__ short Ah[2][64 * 32];    // 2 x 4 KB
    __shared__ short Bh[2][128 * 32];   // 2 x 8 KB

    const int tid  = threadIdx.x;
    const int w    = tid >> 6;
    const int lane = tid & 63;
    const int ln   = lane & 15;
    const int qd   = lane >> 4;
    const int wr   = w >> 1, wc = w & 1;
    const int row0 = blockIdx.y * 64;
    const int col0 = blockIdx.x * 128;

    const int sr = lane >> 2;        // 0..15 staging row-in-chunk
    const int sk = (lane & 3) * 8;   // k element offset
    const int ar  = tid >> 2;        // 0..63 A-convert row
    const int ac8 = (tid & 3) * 8;   // 0,8,16,24

    const float* xp  = x + (size_t)(row0 + ar) * 1024 + ac8;
    const short* bp0 = Bt + (size_t)(col0 + w * 32 + sr) * 1024 + sk;
    const short* bp1 = Bt + (size_t)(col0 + w * 32 + 16 + sr) * 1024 + sk;

    f32x4 acc[2][4];
#pragma unroll
    for (int mi = 0; mi < 2; mi++)
#pragma unroll
        for (int ni = 0; ni < 4; ni++)
            acc[mi][ni] = (f32x4){0.f, 0.f, 0.f, 0.f};

    // prologue: stage tile 0 into buf 0
    {
        float4 a1 = *(const float4*)xp;
        float4 a2 = *(const float4*)(xp + 4);
        bf16x8 o;
        o[0]=f2bf(a1.x); o[1]=f2bf(a1.y); o[2]=f2bf(a1.z); o[3]=f2bf(a1.w);
        o[4]=f2bf(a2.x); o[5]=f2bf(a2.y); o[6]=f2bf(a2.z); o[7]=f2bf(a2.w);
        *(bf16x8*)&Ah[0][ar * 32 + ac8] = o;
    }
    gload_lds16(bp0, &Bh[0][(w * 32) * 32]);
    gload_lds16(bp1, &Bh[0][(w * 32 + 16) * 32]);
    __syncthreads();

    for (int t = 0; t < 32; t++) {
        const int cur = t & 1, nxt = cur ^ 1;
        if (t + 1 < 32) {   // stage next tile first (overlaps MFMA below)
            const int k1 = (t + 1) * 32;
            gload_lds16(bp0 + k1, &Bh[nxt][(w * 32) * 32]);
            gload_lds16(bp1 + k1, &Bh[nxt][(w * 32 + 16) * 32]);
            float4 a1 = *(const float4*)(xp + k1);
            float4 a2 = *(const float4*)(xp + k1 + 4);
            bf16x8 o;
            o[0]=f2bf(a1.x); o[1]=f2bf(a1.y); o[2]=f2bf(a1.z); o[3]=f2bf(a1.w);
            o[4]=f2bf(a2.x); o[5]=f2bf(a2.y); o[6]=f2bf(a2.z); o[7]=f2bf(a2.w);
            *(bf16x8*)&Ah[nxt][ar * 32 + ac8] = o;
        }

        bf16x8 af[2], bfr[4];
#pragma unroll
        for (int mi = 0; mi < 2; mi++)
            af[mi] = *(const bf16x8*)&Ah[cur][(wr * 32 + mi * 16 + ln) * 32 + qd * 8];
#pragma unroll
        for (int ni = 0; ni < 4; ni++)
            bfr[ni] = *(const bf16x8*)&Bh[cur][(wc * 64 + ni * 16 + ln) * 32 + qd * 8];
#pragma unroll
        for (int mi = 0; mi < 2; mi++)
#pragma unroll
            for (int ni = 0; ni < 4; ni++)
                acc[mi][ni] = __builtin_amdgcn_mfma_f32_16x16x32_bf16(af[mi], bfr[ni], acc[mi][ni], 0, 0, 0);

        __syncthreads();   // drain lands after the MFMAs
    }

    const int colw = col0 + wc * 64;          // this wave's 64-col half
    if (colw < H_ + NKV_ * HD_) {
        // ---- q or k columns: RoPE in fp32, store bf16 to qkv ----
#pragma unroll
        for (int mi = 0; mi < 2; mi++)
#pragma unroll
            for (int i = 0; i < 4; i++) {
                const int row  = row0 + wr * 32 + mi * 16 + qd * 4 + i;
                const int spos = row & (S_ - 1);
                const float* cp = cosb + (size_t)spos * HD_;
                const float* sp = sinb + (size_t)spos * HD_;
                float o0[4];
#pragma unroll
                for (int ni = 0; ni < 2; ni++) {
                    const int d = ni * 16 + ln;
                    float x0 = acc[mi][ni][i], x1 = acc[mi][ni + 2][i];
                    o0[ni]     = x0 * cp[d]      - x1 * sp[d];
                    o0[ni + 2] = x1 * cp[d + 32] + x0 * sp[d + 32];
                }
                short* Cp = qkv + (size_t)row * QKVW + colw + ln;
#pragma unroll
                for (int ni = 0; ni < 4; ni++) Cp[ni * 16] = f2bf(o0[ni]);
            }
    } else {
        // ---- v columns: transposed scatter into Vtg[(b*NKV+g)*HD+d][s] ----
        const int g = (colw - (H_ + NKV_ * HD_)) >> 6;
#pragma unroll
        for (int mi = 0; mi < 2; mi++) {
            const int rbase = row0 + wr * 32 + mi * 16 + qd * 4;   // i = +0..3
            const int bg = ((rbase >> 11) * NKV_) + g;
            const int s0 = rbase & (S_ - 1);
#pragma unroll
            for (int ni = 0; ni < 4; ni++) {
                const int d = ni * 16 + ln;
                short4 pk = { f2bf(acc[mi][ni][0]), f2bf(acc[mi][ni][1]),
                              f2bf(acc[mi][ni][2]), f2bf(acc[mi][ni][3]) };
                *(short4*)&Vtg[((size_t)bg * HD_ + d) * S_ + s0] = pk;
            }
        }
    }
}

// ---------------------------------------------------------------------------
// bf16 MFMA GEMM, B^T form: C[M,N] = A[M,K] @ Bt[N,K]^T (fp32 out).
// 64x128 tile, BK=32, 2-phase dbuf (unchanged from R9). Output projection.
// ---------------------------------------------------------------------------
__global__ __launch_bounds__(256) void gemm2_bt(const short* __restrict__ A, int lda,
                                                const short* __restrict__ Bt,
                                                float* __restrict__ C, int ldc,
                                                int K) {
    __shared__ short Ah[2][64 * 32];
    __shared__ short Bh[2][128 * 32];

    const int tid  = threadIdx.x;
    const int w    = tid >> 6;
    const int lane = tid & 63;
    const int ln   = lane & 15;
    const int qd   = lane >> 4;
    const int wr   = w >> 1, wc = w & 1;
    const int row0 = blockIdx.y * 64;
    const int col0 = blockIdx.x * 128;

    const int sr = lane >> 2;
    const int sk = (lane & 3) * 8;

    const short* ap  = A + (size_t)(row0 + w * 16 + sr) * lda + sk;
    const short* bp0 = Bt + (size_t)(col0 + w * 32 + sr) * K + sk;
    const short* bp1 = Bt + (size_t)(col0 + w * 32 + 16 + sr) * K + sk;

    f32x4 acc[2][4];
#pragma unroll
    for (int mi = 0; mi < 2; mi++)
#pragma unroll
        for (int ni = 0; ni < 4; ni++)
            acc[mi][ni] = (f32x4){0.f, 0.f, 0.f, 0.f};

    const int nt = K >> 5;
    gload_lds16(ap,  &Ah[0][(w * 16) * 32]);
    gload_lds16(bp0, &Bh[0][(w * 32) * 32]);
    gload_lds16(bp1, &Bh[0][(w * 32 + 16) * 32]);
    __syncthreads();

    for (int t = 0; t < nt; t++) {
        const int cur = t & 1, nxt = cur ^ 1;
        if (t + 1 < nt) {
            const int k1 = (t + 1) * 32;
            gload_lds16(ap + k1,  &Ah[nxt][(w * 16) * 32]);
            gload_lds16(bp0 + k1, &Bh[nxt][(w * 32) * 32]);
            gload_lds16(bp1 + k1, &Bh[nxt][(w * 32 + 16) * 32]);
        }

        bf16x8 af[2], bfr[4];
#pragma unroll
        for (int mi = 0; mi < 2; mi++)
            af[mi] = *(const bf16x8*)&Ah[cur][(wr * 32 + mi * 16 + ln) * 32 + qd * 8];
#pragma unroll
        for (int ni = 0; ni < 4; ni++)
            bfr[ni] = *(const bf16x8*)&Bh[cur][(wc * 64 + ni * 16 + ln) * 32 + qd * 8];
#pragma unroll
        for (int mi = 0; mi < 2; mi++)
#pragma unroll
            for (int ni = 0; ni < 4; ni++)
                acc[mi][ni] = __builtin_amdgcn_mfma_f32_16x16x32_bf16(af[mi], bfr[ni], acc[mi][ni], 0, 0, 0);

        __syncthreads();
    }

#pragma unroll
    for (int mi = 0; mi < 2; mi++)
#pragma unroll
        for (int i = 0; i < 4; i++) {
            const size_t row = row0 + wr * 32 + mi * 16 + qd * 4 + i;
            float* Cp = C + row * ldc + col0 + wc * 64 + ln;
#pragma unroll
            for (int ni = 0; ni < 4; ni++) Cp[ni * 16] = acc[mi][ni][i];
        }
}

// ---------------------------------------------------------------------------
// bf16 MFMA flash attention v18: KVBLK=128, 17 uniform macro-steps.
//   R9 post-mortem: v17's 34 steps each pay fixed costs (2 shfl-reduces,
//   ballot/rescale, barriers, pack turnaround) per 64 keys; waves are
//   barrier-locked into the same burst phase. v18 halves the step count:
//   - 128-key tiles: phase qt needs qt+1 tiles; pair total = 17 for EVERY a.
//   - Every wave's diagonal is the LAST tile (no sparse steps at all);
//     wave-uniform guards kg<=w / kc2<=w/2 skip truly-masked MFMAs there.
//   - Single-buffered K/V (53 KB static LDS) + register prefetch:
//     {prefetch-issue -> compute -> barrier -> prefetch-write -> barrier}.
//   - Ps = [16][72]/wave; pack+PV in two 64-key halves (same-wave in-order
//     ds write->read).
//   - T5 setprio(1) around QK and PV MFMA clusters.
//   - log2-domain softmax + cvt_pk pack (R8-proven).
// ---------------------------------------------------------------------------
__global__ __launch_bounds__(512, 1) void attn_kernel(short* __restrict__ qkv,
                                                      const short* __restrict__ Vtg,
                                                      const float* __restrict__ maskb) {
    const int tid  = threadIdx.x;
    const int w    = tid >> 6;           // 0..7
    const int lane = tid & 63;
    const int ln   = lane & 15;
    const int qd   = lane >> 4;

    // fid&7 = bg -> XCD affinity for the K/V slice
    const int fid = blockIdx.x;          // 0..255
    const int bg  = fid & 7;             // b*NKV+g
    const int u   = fid >> 3;            // 0..31
    const int b   = bg >> 2;
    const int g   = bg & 3;
    const int h   = g * R_ + (u & 3);
    const int a   = u >> 2;              // pair index 0..7

    __shared__ short Ks[128 * 72];       // K  [key][dim], stride 72 (36 KB->18.4KB)
    __shared__ short Vt[64 * 136];       // V^T [dim][key], stride 136 (17.4KB)
    __shared__ short Ps[8][16 * 72];     // per-wave P half-tile (18.4KB)
    short* const ps = Ps[w];

    const short* const Kb = qkv + (size_t)b * S_ * QKVW + H_ + g * HD_;
    const short* const Vb = Vtg + (size_t)bg * HD_ * S_;
    const float* const mb = maskb + b * S_;

    const int kr = tid >> 2;             // 0..127  K staging row
    const int kc = (tid & 3) * 16;       // 0,16,32,48 (shorts)
    const int vr = tid >> 3;             // 0..63   V staging row
    const int vc = (tid & 7) * 16;       // 0..112

#pragma unroll 1
    for (int ph = 0; ph < 2; ph++) {
        const int qt   = ph ? (15 - a) : a;
        const int rowb = qt * 128 + w * 16;   // this wave's 16-row strip
        const int ntp  = qt + 1;              // 128-key tiles this phase
        const int qrow = rowb + ln;

        // ---- Q B-frags: rows rowb+ln ----
        bf16x8 qf0, qf1;
        {
            const short* qp = qkv + (size_t)(b * S_ + rowb + ln) * QKVW + h * HD_;
            qf0 = *(const bf16x8*)&qp[qd * 8];
            qf1 = *(const bf16x8*)&qp[32 + qd * 8];
        }

        f32x4 O[4] = {};
        float mrow = -1e30f, lrow = 0.0f;    // mrow in log2 units

        // ---- stage tile 0 ----
        *(bf16x8*)&Ks[kr * 72 + kc]      = *(const bf16x8*)&Kb[(size_t)kr * QKVW + kc];
        *(bf16x8*)&Ks[kr * 72 + kc + 8]  = *(const bf16x8*)&Kb[(size_t)kr * QKVW + kc + 8];
        *(bf16x8*)&Vt[vr * 136 + vc]     = *(const bf16x8*)&Vb[(size_t)vr * S_ + vc];
        *(bf16x8*)&Vt[vr * 136 + vc + 8] = *(const bf16x8*)&Vb[(size_t)vr * S_ + vc + 8];
        __syncthreads();

#pragma unroll 1
        for (int kt = 0; kt < ntp; kt++) {
            const int base = kt * 128;
            const bool pf = (kt + 1 < ntp);

            // ---- prefetch tile kt+1 into registers (no wait) ----
            bf16x8 pk0, pk1, pv0, pv1;
            if (pf) {
                const int nb = base + 128;
                pk0 = *(const bf16x8*)&Kb[(size_t)(nb + kr) * QKVW + kc];
                pk1 = *(const bf16x8*)&Kb[(size_t)(nb + kr) * QKVW + kc + 8];
                pv0 = *(const bf16x8*)&Vb[(size_t)vr * S_ + nb + vc];
                pv1 = *(const bf16x8*)&Vb[(size_t)vr * S_ + nb + vc + 8];
            }

            const bool diag  = (kt == ntp - 1);
            const int kgmax  = diag ? (w + 1) : 8;        // QK groups needed
            const int c2max  = diag ? ((w >> 1) + 1) : 4; // PV 32-key chunks

            // ---- QK^T swapped: St[kg] = S^T[key][qrow=ln] ----
            f32x4 St[8];
            __builtin_amdgcn_s_setprio(1);
#pragma unroll
            for (int kg = 0; kg < 8; kg++) {
                if (kg < kgmax) {
                    bf16x8 ka0 = *(const bf16x8*)&Ks[(kg * 16 + ln) * 72 + qd * 8];
                    bf16x8 ka1 = *(const bf16x8*)&Ks[(kg * 16 + ln) * 72 + 32 + qd * 8];
                    f32x4 z = {0.f, 0.f, 0.f, 0.f};
                    z = __builtin_amdgcn_mfma_f32_16x16x32_bf16(ka0, qf0, z, 0, 0, 0);
                    St[kg] = __builtin_amdgcn_mfma_f32_16x16x32_bf16(ka1, qf1, z, 0, 0, 0);
                }
            }
            __builtin_amdgcn_s_setprio(0);

            // ---- scale + mask bias (log2 domain), in place ----
            const float MX = 1e9f * LOG2E;
#pragma unroll
            for (int kg = 0; kg < 8; kg++) {
                float4 mv = *(const float4*)&mb[base + kg * 16 + qd * 4];
                St[kg][0] = fmaf(St[kg][0], 0.125f * LOG2E, fmaf(mv.x, MX, -MX));
                St[kg][1] = fmaf(St[kg][1], 0.125f * LOG2E, fmaf(mv.y, MX, -MX));
                St[kg][2] = fmaf(St[kg][2], 0.125f * LOG2E, fmaf(mv.z, MX, -MX));
                St[kg][3] = fmaf(St[kg][3], 0.125f * LOG2E, fmaf(mv.w, MX, -MX));
            }
            if (diag) {   // causal: also covers kg >= kgmax (St garbage -> masked)
#pragma unroll
                for (int kg = 0; kg < 8; kg++) {
                    const int keyb = base + kg * 16 + qd * 4;
#pragma unroll
                    for (int i = 0; i < 4; i++)
                        if (keyb + i > qrow) St[kg][i] = -1e30f;
                }
            }

            float mx = St[0][0];
#pragma unroll
            for (int kg = 0; kg < 8; kg++)
#pragma unroll
                for (int i = 0; i < 4; i++) mx = fmaxf(mx, St[kg][i]);
            mx = fmaxf(mx, __shfl_xor(mx, 16));
            mx = fmaxf(mx, __shfl_xor(mx, 32));

            // defer-max (T13): 8 ln-units = 11.5416 log2-units
            if (__ballot(mx > mrow + 11.5416f)) {
                float nm    = fmaxf(mrow, mx);
                float alpha = exp2fast(mrow - nm);
                lrow *= alpha;
#pragma unroll
                for (int i = 0; i < 4; i++) {
                    float av = __shfl(alpha, qd * 4 + i);
#pragma unroll
                    for (int dt = 0; dt < 4; dt++) O[dt][i] *= av;
                }
                mrow = nm;
            }
            const float nm = mrow;

            float ls = 0.0f;
#pragma unroll
            for (int kg = 0; kg < 8; kg++)
#pragma unroll
                for (int i = 0; i < 4; i++) {
                    float p = exp2fast(St[kg][i] - nm);
                    St[kg][i] = p;
                    ls += p;
                }
            ls += __shfl_xor(ls, 16);
            ls += __shfl_xor(ls, 32);
            lrow += ls;

            // ---- pack + PV in two 64-key halves (same-wave in-order ds) ----
            __builtin_amdgcn_s_setprio(1);
#pragma unroll
            for (int hh = 0; hh < 2; hh++) {
                if (hh * 2 < c2max) {
#pragma unroll
                    for (int k4 = 0; k4 < 4; k4++) {
                        const int kg = hh * 4 + k4;
                        uint2 pw;
                        pw.x = cvt_pk_bf16(St[kg][0], St[kg][1]);
                        pw.y = cvt_pk_bf16(St[kg][2], St[kg][3]);
                        *(uint2*)&ps[ln * 72 + k4 * 16 + qd * 4] = pw;
                    }
#pragma unroll
                    for (int c2 = 0; c2 < 2; c2++) {
                        const int kc2 = hh * 2 + c2;
                        if (kc2 < c2max) {
                            bf16x8 pa = *(const bf16x8*)&ps[ln * 72 + c2 * 32 + qd * 8];
#pragma unroll
                            for (int dt = 0; dt < 4; dt++) {
                                bf16x8 vb = *(const bf16x8*)&Vt[(dt * 16 + ln) * 136 + kc2 * 32 + qd * 8];
                                O[dt] = __builtin_amdgcn_mfma_f32_16x16x32_bf16(pa, vb, O[dt], 0, 0, 0);
                            }
                        }
                    }
                }
            }
            __builtin_amdgcn_s_setprio(0);

            // ---- publish prefetched tile (all readers done at barrier) ----
            __syncthreads();
            if (pf) {
                *(bf16x8*)&Ks[kr * 72 + kc]      = pk0;
                *(bf16x8*)&Ks[kr * 72 + kc + 8]  = pk1;
                *(bf16x8*)&Vt[vr * 136 + vc]     = pv0;
                *(bf16x8*)&Vt[vr * 136 + vc + 8] = pv1;
            }
            __syncthreads();
        }

        // ---- finalize this phase: write bf16 into q-slice ----
#pragma unroll
        for (int i = 0; i < 4; i++) {
            float li  = __shfl(lrow, qd * 4 + i);
            float inv = 1.0f / li;
            const int row = rowb + qd * 4 + i;
            short* op = qkv + (size_t)(b * S_ + row) * QKVW + h * HD_ + ln;
#pragma unroll
            for (int dt = 0; dt < 4; dt++) op[dt * 16] = f2bf(O[dt][i] * inv);
        }
    }
}

// ---------------------------------------------------------------------------
extern "C" void kernel_launch(void* const* d_in, const int* in_sizes, int n_in,
                              void* d_out, int out_size, void* d_ws, size_t ws_size,
                              hipStream_t stream) {
    const float* x     = (const float*)d_in[0];
    const float* cosb  = (const float*)d_in[1];
    const float* sinb  = (const float*)d_in[2];
    const float* maskb = (const float*)d_in[3];
    const float* Wq    = (const float*)d_in[4];
    const float* Wk    = (const float*)d_in[5];
    const float* Wv    = (const float*)d_in[6];
    const float* Wo    = (const float*)d_in[7];

    const int M = B_ * S_;   // 4096

    // ws: qkv | Wqkvt | Wot | Vtg  (19.9 MB bf16). d_out only for out.
    short* qkv   = (short*)d_ws;                     // [4096][1536]
    short* Wqkvt = qkv + (size_t)M * QKVW;           // [1536][1024]
    short* Wot   = Wqkvt + (size_t)QKVW * H_;        // [1024][1024]
    short* Vtg   = Wot + (size_t)H_ * H_;            // [8*64][2048]
    float* out   = (float*)d_out;

    dim3 blk(256);

    // weight transposes
    tconv_all<<<dim3(640), blk, 0, stream>>>(Wq, Wk, Wv, Wo, Wqkvt, Wot);

    // GEMM1 fused (64x128, 2-phase dbuf, A-convert fused from fp32 x)
    gemm1_fused<<<dim3(QKVW / 128, M / 64), blk, 0, stream>>>(x, Wqkvt, qkv, Vtg, cosb, sinb);

    // attention: 256 pair-blocks x 512 threads, 17 uniform 128-key steps
    attn_kernel<<<dim3(256), dim3(512), 0, stream>>>(qkv, Vtg, maskb);

    // GEMM2 (64x128, 2-phase dbuf): out = attn @ Wot^T
    gemm2_bt<<<dim3(H_ / 128, M / 64), blk, 0, stream>>>(qkv, QKVW, Wot, out, H_, H_);
}